// Round 1
// baseline (849.699 us; speedup 1.0000x reference)
//
#include <hip/hip_runtime.h>
#include <math.h>

// Problem constants (from setup_inputs): B=2, C=256, N=4096
#define NB 2
#define NC 256
#define NN 4096
#define N4 (NN / 4)          // 1024 float4 per row
#define CHUNKS 64            // row-chunks for K^T a partials
#define ROWS_PER_CHUNK (NN / CHUNKS)  // 64
#define MAX_ITER 10

// ---------------------------------------------------------------------------
// 1) inv_norm[b,n] = 1/sqrt(sum_c feats[b,c,n]^2 + 1e-6)
// grid: (NN/256, NB, 2), block 256. Coalesced along n.
__global__ __launch_bounds__(256) void norms_kernel(
    const float* __restrict__ f1, const float* __restrict__ f2,
    float* __restrict__ inv1, float* __restrict__ inv2) {
  int n = blockIdx.x * 256 + threadIdx.x;
  int b = blockIdx.y;
  const float* f = blockIdx.z ? f2 : f1;
  float* o = blockIdx.z ? inv2 : inv1;
  const float* base = f + (size_t)b * NC * NN + n;
  float s = 0.f;
#pragma unroll 8
  for (int c = 0; c < NC; ++c) {
    float v = base[(size_t)c * NN];
    s = fmaf(v, v, s);
  }
  o[b * NN + n] = 1.0f / sqrtf(s + 1e-6f);
}

// ---------------------------------------------------------------------------
// 2) K[b,i,j] = exp((corr-1)/eps') * (dist < 0.25), corr = rawdot*inv1*inv2
// TN GEMM: rawdot[i,j] = sum_c f1[b,c,i]*f2[b,c,j]. 64x64 tile, BK=16,
// 256 threads, 4x4 microtile per thread.
__global__ __launch_bounds__(256) void kmat_kernel(
    const float* __restrict__ f1, const float* __restrict__ f2,
    const float* __restrict__ pc1, const float* __restrict__ pc2,
    const float* __restrict__ inv1, const float* __restrict__ inv2,
    const float* __restrict__ g_eps, float* __restrict__ K) {
  int b = blockIdx.z;
  int i0 = blockIdx.y * 64;
  int j0 = blockIdx.x * 64;
  const float* A = f1 + (size_t)b * NC * NN;  // [C][N]
  const float* Bp = f2 + (size_t)b * NC * NN;

  __shared__ float As[16][64];
  __shared__ float Bs[16][64];
  __shared__ float p1s[3][64], p2s[3][64];
  __shared__ float i1s[64], i2s[64];

  int tid = threadIdx.x;
  if (tid < 192) {
    int d = tid >> 6, c = tid & 63;
    p1s[d][c] = pc1[((size_t)b * 3 + d) * NN + i0 + c];
    p2s[d][c] = pc2[((size_t)b * 3 + d) * NN + j0 + c];
  }
  if (tid < 64) {
    i1s[tid] = inv1[b * NN + i0 + tid];
  } else if (tid < 128) {
    i2s[tid - 64] = inv2[b * NN + j0 + tid - 64];
  }
  float inv_eps = 1.0f / (expf(g_eps[0]) + 0.03f);

  float acc[4][4] = {};
  int ty = tid >> 4, tx = tid & 15;

  for (int kk = 0; kk < NC; kk += 16) {
    __syncthreads();  // also covers visibility of p1s/p2s/i1s/i2s on kk==0
#pragma unroll
    for (int q = 0; q < 4; ++q) {
      int t = tid + q * 256;
      int r = t >> 6, c = t & 63;
      As[r][c] = A[(size_t)(kk + r) * NN + i0 + c];
      Bs[r][c] = Bp[(size_t)(kk + r) * NN + j0 + c];
    }
    __syncthreads();
#pragma unroll
    for (int k = 0; k < 16; ++k) {
      float ar[4], br[4];
#pragma unroll
      for (int u = 0; u < 4; ++u) ar[u] = As[k][ty * 4 + u];
#pragma unroll
      for (int v = 0; v < 4; ++v) br[v] = Bs[k][tx * 4 + v];
#pragma unroll
      for (int u = 0; u < 4; ++u)
#pragma unroll
        for (int v = 0; v < 4; ++v) acc[u][v] = fmaf(ar[u], br[v], acc[u][v]);
    }
  }

  // Epilogue: dist + support + exp, float4 stores (coalesced along j).
#pragma unroll
  for (int u = 0; u < 4; ++u) {
    int ii = ty * 4 + u;
    int i = i0 + ii;
    float p1x = p1s[0][ii], p1y = p1s[1][ii], p1z = p1s[2][ii];
    float n1 = p1x * p1x + p1y * p1y + p1z * p1z;
    float kvarr[4];
#pragma unroll
    for (int v = 0; v < 4; ++v) {
      int jj = tx * 4 + v;
      float p2x = p2s[0][jj], p2y = p2s[1][jj], p2z = p2s[2][jj];
      float n2 = p2x * p2x + p2y * p2y + p2z * p2z;
      float dot = p1x * p2x + p1y * p2y + p1z * p2z;
      float dist = n1 + n2 - 2.0f * dot;           // reference formula
      float corr = acc[u][v] * i1s[ii] * i2s[jj];
      kvarr[v] = (dist < 0.25f) ? expf((corr - 1.0f) * inv_eps) : 0.0f;
    }
    *(float4*)&K[((size_t)b * NN + i) * NN + j0 + tx * 4] = *(float4*)kvarr;
  }
}

// ---------------------------------------------------------------------------
// 3) a init: a = 1/N
__global__ void init_a_kernel(float* __restrict__ a) {
  int idx = blockIdx.x * 256 + threadIdx.x;
  if (idx < NB * NN) a[idx] = 1.0f / NN;
}

// 4) K^T a partials: part[chunk,b,j] = sum_{i in chunk} K[b,i,j]*a[b,i]
// grid: (N4/256=4, CHUNKS=64, NB=2) -> 512 blocks; float4 columns.
__global__ __launch_bounds__(256) void kta_kernel(
    const float* __restrict__ K, const float* __restrict__ a,
    float* __restrict__ part) {
  int b = blockIdx.z;
  int chunk = blockIdx.y;
  int j4 = blockIdx.x * 256 + threadIdx.x;  // 0..N4-1
  const float4* K4 = (const float4*)(K + (size_t)b * NN * NN);
  const float* av = a + b * NN;
  float4 s = {0.f, 0.f, 0.f, 0.f};
  int i0 = chunk * ROWS_PER_CHUNK;
#pragma unroll 4
  for (int r = 0; r < ROWS_PER_CHUNK; ++r) {
    int i = i0 + r;
    float w = av[i];
    float4 k4 = K4[(size_t)i * N4 + j4];
    s.x = fmaf(k4.x, w, s.x);
    s.y = fmaf(k4.y, w, s.y);
    s.z = fmaf(k4.z, w, s.z);
    s.w = fmaf(k4.w, w, s.w);
  }
  ((float4*)part)[((size_t)chunk * NB + b) * N4 + j4] = s;
}

// 5) b[j] = (prob2/(KTa[j]+1e-8))^power  (sums the partials)
__global__ __launch_bounds__(256) void b_kernel(
    const float* __restrict__ part, float* __restrict__ bvec,
    const float* __restrict__ g_gamma, const float* __restrict__ g_eps) {
  int b = blockIdx.y;
  int j4 = blockIdx.x * 256 + threadIdx.x;
  const float4* p4 = (const float4*)part;
  float4 s = {0.f, 0.f, 0.f, 0.f};
  for (int c = 0; c < CHUNKS; ++c) {
    float4 v = p4[((size_t)c * NB + b) * N4 + j4];
    s.x += v.x; s.y += v.y; s.z += v.z; s.w += v.w;
  }
  float eps = expf(g_eps[0]) + 0.03f;
  float gam = expf(g_gamma[0]) + 0.03f;
  float power = gam / (gam + eps);
  const float prob2 = 1.0f / NN;
  float4 r;
  r.x = powf(prob2 / (s.x + 1e-8f), power);
  r.y = powf(prob2 / (s.y + 1e-8f), power);
  r.z = powf(prob2 / (s.z + 1e-8f), power);
  r.w = powf(prob2 / (s.w + 1e-8f), power);
  ((float4*)(bvec + b * NN))[j4] = r;
}

// 6) Kb row sums fused with a update: a[i] = (prob1/(Kb[i]+1e-8))^power
// grid: (NN, NB), block 256 — one block per row.
__global__ __launch_bounds__(256) void kb_a_kernel(
    const float* __restrict__ K, const float* __restrict__ bvec,
    float* __restrict__ a, const float* __restrict__ g_gamma,
    const float* __restrict__ g_eps) {
  int b = blockIdx.y;
  int i = blockIdx.x;
  const float4* K4 = (const float4*)(K + ((size_t)b * NN + i) * NN);
  const float4* b4 = (const float4*)(bvec + b * NN);
  float s = 0.f;
  for (int j4 = threadIdx.x; j4 < N4; j4 += 256) {
    float4 k = K4[j4];
    float4 bb = b4[j4];
    s += k.x * bb.x + k.y * bb.y + k.z * bb.z + k.w * bb.w;
  }
#pragma unroll
  for (int off = 32; off; off >>= 1) s += __shfl_down(s, off, 64);
  __shared__ float sbuf[4];
  int lane = threadIdx.x & 63, wid = threadIdx.x >> 6;
  if (lane == 0) sbuf[wid] = s;
  __syncthreads();
  if (threadIdx.x == 0) {
    float kb = sbuf[0] + sbuf[1] + sbuf[2] + sbuf[3];
    float eps = expf(g_eps[0]) + 0.03f;
    float gam = expf(g_gamma[0]) + 0.03f;
    float power = gam / (gam + eps);
    a[b * NN + i] = powf((1.0f / NN) / (kb + 1e-8f), power);
  }
}

// 7) flow[i] = a_i*S{xyz}/(a_i*S + 1e-6) - p1_i,  S* = sum_j K[i,j]b[j]*{1,p2}
__global__ __launch_bounds__(256) void flow_kernel(
    const float* __restrict__ K, const float* __restrict__ a,
    const float* __restrict__ bvec, const float* __restrict__ pc1,
    const float* __restrict__ pc2, float* __restrict__ out) {
  int b = blockIdx.y;
  int i = blockIdx.x;
  const float4* K4 = (const float4*)(K + ((size_t)b * NN + i) * NN);
  const float4* b4 = (const float4*)(bvec + b * NN);
  const float4* p2x = (const float4*)(pc2 + (size_t)b * 3 * NN);
  const float4* p2y = p2x + N4;
  const float4* p2z = p2y + N4;
  float S = 0.f, Sx = 0.f, Sy = 0.f, Sz = 0.f;
  for (int j4 = threadIdx.x; j4 < N4; j4 += 256) {
    float4 k = K4[j4];
    float4 bb = b4[j4];
    float w0 = k.x * bb.x, w1 = k.y * bb.y, w2 = k.z * bb.z, w3 = k.w * bb.w;
    float4 x = p2x[j4], y = p2y[j4], z = p2z[j4];
    S += w0 + w1 + w2 + w3;
    Sx += w0 * x.x + w1 * x.y + w2 * x.z + w3 * x.w;
    Sy += w0 * y.x + w1 * y.y + w2 * y.z + w3 * y.w;
    Sz += w0 * z.x + w1 * z.y + w2 * z.z + w3 * z.w;
  }
#pragma unroll
  for (int off = 32; off; off >>= 1) {
    S += __shfl_down(S, off, 64);
    Sx += __shfl_down(Sx, off, 64);
    Sy += __shfl_down(Sy, off, 64);
    Sz += __shfl_down(Sz, off, 64);
  }
  __shared__ float red[4][4];
  int lane = threadIdx.x & 63, wid = threadIdx.x >> 6;
  if (lane == 0) {
    red[wid][0] = S; red[wid][1] = Sx; red[wid][2] = Sy; red[wid][3] = Sz;
  }
  __syncthreads();
  if (threadIdx.x == 0) {
    float St = red[0][0] + red[1][0] + red[2][0] + red[3][0];
    float Sxt = red[0][1] + red[1][1] + red[2][1] + red[3][1];
    float Syt = red[0][2] + red[1][2] + red[2][2] + red[3][2];
    float Szt = red[0][3] + red[1][3] + red[2][3] + red[3][3];
    float av = a[b * NN + i];
    float denom = av * St + 1e-6f;
    const float* p1 = pc1 + (size_t)b * 3 * NN;
    size_t o = ((size_t)b * NN + i) * 3;
    out[o + 0] = av * Sxt / denom - p1[0 * NN + i];
    out[o + 1] = av * Syt / denom - p1[1 * NN + i];
    out[o + 2] = av * Szt / denom - p1[2 * NN + i];
  }
}

// ---------------------------------------------------------------------------
extern "C" void kernel_launch(void* const* d_in, const int* in_sizes, int n_in,
                              void* d_out, int out_size, void* d_ws,
                              size_t ws_size, hipStream_t stream) {
  const float* pc1 = (const float*)d_in[0];
  const float* pc2 = (const float*)d_in[1];
  const float* f1 = (const float*)d_in[2];
  const float* f2 = (const float*)d_in[3];
  const float* g_gamma = (const float*)d_in[4];
  const float* g_eps = (const float*)d_in[5];
  float* out = (float*)d_out;

  // Workspace layout
  size_t off = 0;
  char* ws = (char*)d_ws;
  float* K = (float*)(ws + off);    off += (size_t)NB * NN * NN * sizeof(float);   // 134 MB
  float* inv1 = (float*)(ws + off); off += (size_t)NB * NN * sizeof(float);
  float* inv2 = (float*)(ws + off); off += (size_t)NB * NN * sizeof(float);
  float* avec = (float*)(ws + off); off += (size_t)NB * NN * sizeof(float);
  float* bvec = (float*)(ws + off); off += (size_t)NB * NN * sizeof(float);
  float* part = (float*)(ws + off); off += (size_t)CHUNKS * NB * NN * sizeof(float); // 2 MB
  if (ws_size < off) return;  // workspace too small — fail loudly via mismatch

  norms_kernel<<<dim3(NN / 256, NB, 2), 256, 0, stream>>>(f1, f2, inv1, inv2);
  kmat_kernel<<<dim3(NN / 64, NN / 64, NB), 256, 0, stream>>>(
      f1, f2, pc1, pc2, inv1, inv2, g_eps, K);
  init_a_kernel<<<(NB * NN + 255) / 256, 256, 0, stream>>>(avec);

  for (int it = 0; it < MAX_ITER; ++it) {
    kta_kernel<<<dim3(N4 / 256, CHUNKS, NB), 256, 0, stream>>>(K, avec, part);
    b_kernel<<<dim3(N4 / 256, NB), 256, 0, stream>>>(part, bvec, g_gamma, g_eps);
    kb_a_kernel<<<dim3(NN, NB), 256, 0, stream>>>(K, bvec, avec, g_gamma, g_eps);
  }
  flow_kernel<<<dim3(NN, NB), 256, 0, stream>>>(K, avec, bvec, pc1, pc2, out);
}

// Round 2
// 654.108 us; speedup vs baseline: 1.2990x; 1.2990x over previous
//
#include <hip/hip_runtime.h>
#include <hip/hip_fp16.h>
#include <math.h>

// Problem constants (from setup_inputs): B=2, C=256, N=4096
#define NB 2
#define NC 256
#define NN 4096
#define N4 (NN / 4)                    // 1024 float4 per row
#define N8 (NN / 8)                    // 512 half8 (16B) per row
#define CHUNKS 128                     // row-chunks for K^T a partials
#define ROWS_PER_CHUNK (NN / CHUNKS)   // 32
#define MAX_ITER 10

union H8 { uint4 u; __half2 h[4]; };

// ---------------------------------------------------------------------------
// 1) inv_norm[b,n] = 1/sqrt(sum_c feats[b,c,n]^2 + 1e-6)
__global__ __launch_bounds__(256) void norms_kernel(
    const float* __restrict__ f1, const float* __restrict__ f2,
    float* __restrict__ inv1, float* __restrict__ inv2) {
  int n = blockIdx.x * 256 + threadIdx.x;
  int b = blockIdx.y;
  const float* f = blockIdx.z ? f2 : f1;
  float* o = blockIdx.z ? inv2 : inv1;
  const float* base = f + (size_t)b * NC * NN + n;
  float s = 0.f;
#pragma unroll 8
  for (int c = 0; c < NC; ++c) {
    float v = base[(size_t)c * NN];
    s = fmaf(v, v, s);
  }
  o[b * NN + n] = 1.0f / sqrtf(s + 1e-6f);
}

// ---------------------------------------------------------------------------
// 2) K[b,i,j] = exp((corr-1)/eps') * (dist < 0.25), corr = rawdot*inv1*inv2
// TN GEMM fp32, K stored fp16. 64x64 tile, BK=16, 256 threads, 4x4 microtile.
__global__ __launch_bounds__(256) void kmat_kernel(
    const float* __restrict__ f1, const float* __restrict__ f2,
    const float* __restrict__ pc1, const float* __restrict__ pc2,
    const float* __restrict__ inv1, const float* __restrict__ inv2,
    const float* __restrict__ g_eps, __half* __restrict__ K) {
  int b = blockIdx.z;
  int i0 = blockIdx.y * 64;
  int j0 = blockIdx.x * 64;
  const float* A = f1 + (size_t)b * NC * NN;  // [C][N]
  const float* Bp = f2 + (size_t)b * NC * NN;

  __shared__ float As[16][64];
  __shared__ float Bs[16][64];
  __shared__ float p1s[3][64], p2s[3][64];
  __shared__ float i1s[64], i2s[64];

  int tid = threadIdx.x;
  if (tid < 192) {
    int d = tid >> 6, c = tid & 63;
    p1s[d][c] = pc1[((size_t)b * 3 + d) * NN + i0 + c];
    p2s[d][c] = pc2[((size_t)b * 3 + d) * NN + j0 + c];
  }
  if (tid < 64) {
    i1s[tid] = inv1[b * NN + i0 + tid];
  } else if (tid < 128) {
    i2s[tid - 64] = inv2[b * NN + j0 + tid - 64];
  }
  float inv_eps = 1.0f / (expf(g_eps[0]) + 0.03f);

  float acc[4][4] = {};
  int ty = tid >> 4, tx = tid & 15;

  for (int kk = 0; kk < NC; kk += 16) {
    __syncthreads();  // also covers visibility of p1s/p2s/i1s/i2s on kk==0
#pragma unroll
    for (int q = 0; q < 4; ++q) {
      int t = tid + q * 256;
      int r = t >> 6, c = t & 63;
      As[r][c] = A[(size_t)(kk + r) * NN + i0 + c];
      Bs[r][c] = Bp[(size_t)(kk + r) * NN + j0 + c];
    }
    __syncthreads();
#pragma unroll
    for (int k = 0; k < 16; ++k) {
      float4 ar = *(const float4*)&As[k][ty * 4];
      float4 br = *(const float4*)&Bs[k][tx * 4];
      float arr[4] = {ar.x, ar.y, ar.z, ar.w};
      float brr[4] = {br.x, br.y, br.z, br.w};
#pragma unroll
      for (int u = 0; u < 4; ++u)
#pragma unroll
        for (int v = 0; v < 4; ++v)
          acc[u][v] = fmaf(arr[u], brr[v], acc[u][v]);
    }
  }

  // Epilogue: dist + support + exp, fp16 stores (8B per thread, coalesced).
#pragma unroll
  for (int u = 0; u < 4; ++u) {
    int ii = ty * 4 + u;
    int i = i0 + ii;
    float p1x = p1s[0][ii], p1y = p1s[1][ii], p1z = p1s[2][ii];
    float n1 = p1x * p1x + p1y * p1y + p1z * p1z;
    float kv[4];
#pragma unroll
    for (int v = 0; v < 4; ++v) {
      int jj = tx * 4 + v;
      float p2x = p2s[0][jj], p2y = p2s[1][jj], p2z = p2s[2][jj];
      float n2 = p2x * p2x + p2y * p2y + p2z * p2z;
      float dot = p1x * p2x + p1y * p2y + p1z * p2z;
      float dist = n1 + n2 - 2.0f * dot;           // reference formula
      float corr = acc[u][v] * i1s[ii] * i2s[jj];
      kv[v] = (dist < 0.25f) ? __expf((corr - 1.0f) * inv_eps) : 0.0f;
    }
    __half2 h01 = __floats2half2_rn(kv[0], kv[1]);
    __half2 h23 = __floats2half2_rn(kv[2], kv[3]);
    uint2 pack;
    pack.x = *(unsigned int*)&h01;
    pack.y = *(unsigned int*)&h23;
    *(uint2*)&K[((size_t)b * NN + i) * NN + j0 + tx * 4] = pack;
  }
}

// ---------------------------------------------------------------------------
// 3) a init: a = 1/N
__global__ void init_a_kernel(float* __restrict__ a) {
  int idx = blockIdx.x * 256 + threadIdx.x;
  if (idx < NB * NN) a[idx] = 1.0f / NN;
}

// 4) K^T a partials: part[chunk,b,j] = sum_{i in chunk} K[b,i,j]*a[b,i]
// grid: (N8/256=2, CHUNKS=128, NB=2) -> 512 blocks; 16B fp16 column loads.
__global__ __launch_bounds__(256) void kta_kernel(
    const __half* __restrict__ K, const float* __restrict__ a,
    float* __restrict__ part) {
  int b = blockIdx.z;
  int chunk = blockIdx.y;
  int j8 = blockIdx.x * 256 + threadIdx.x;  // 0..N8-1
  const uint4* K8 = (const uint4*)(K + (size_t)b * NN * NN);
  const float* av = a + b * NN;
  float s[8] = {};
  int i0 = chunk * ROWS_PER_CHUNK;
#pragma unroll 4
  for (int r = 0; r < ROWS_PER_CHUNK; ++r) {
    int i = i0 + r;
    float w = av[i];
    H8 k;
    k.u = K8[(size_t)i * N8 + j8];
#pragma unroll
    for (int q = 0; q < 4; ++q) {
      float2 f = __half22float2(k.h[q]);
      s[2 * q]     = fmaf(f.x, w, s[2 * q]);
      s[2 * q + 1] = fmaf(f.y, w, s[2 * q + 1]);
    }
  }
  float4* p = (float4*)(part + ((size_t)chunk * NB + b) * NN + j8 * 8);
  p[0] = make_float4(s[0], s[1], s[2], s[3]);
  p[1] = make_float4(s[4], s[5], s[6], s[7]);
}

// 5) b[j] = (prob2/(KTa[j]+1e-8))^power  (sums the partials)
__global__ __launch_bounds__(256) void b_kernel(
    const float* __restrict__ part, float* __restrict__ bvec,
    const float* __restrict__ g_gamma, const float* __restrict__ g_eps) {
  int b = blockIdx.y;
  int j4 = blockIdx.x * 256 + threadIdx.x;
  const float4* p4 = (const float4*)part;
  float4 s = {0.f, 0.f, 0.f, 0.f};
  for (int c = 0; c < CHUNKS; ++c) {
    float4 v = p4[((size_t)c * NB + b) * N4 + j4];
    s.x += v.x; s.y += v.y; s.z += v.z; s.w += v.w;
  }
  float eps = expf(g_eps[0]) + 0.03f;
  float gam = expf(g_gamma[0]) + 0.03f;
  float power = gam / (gam + eps);
  const float prob2 = 1.0f / NN;
  float4 r;
  r.x = powf(prob2 / (s.x + 1e-8f), power);
  r.y = powf(prob2 / (s.y + 1e-8f), power);
  r.z = powf(prob2 / (s.z + 1e-8f), power);
  r.w = powf(prob2 / (s.w + 1e-8f), power);
  ((float4*)(bvec + b * NN))[j4] = r;
}

// 6) Kb row sums fused with a update: a[i] = (prob1/(Kb[i]+1e-8))^power
__global__ __launch_bounds__(256) void kb_a_kernel(
    const __half* __restrict__ K, const float* __restrict__ bvec,
    float* __restrict__ a, const float* __restrict__ g_gamma,
    const float* __restrict__ g_eps) {
  int b = blockIdx.y;
  int i = blockIdx.x;
  const uint4* K8 = (const uint4*)(K + ((size_t)b * NN + i) * NN);
  const float4* b4 = (const float4*)(bvec + b * NN);
  float s = 0.f;
  for (int j8 = threadIdx.x; j8 < N8; j8 += 256) {
    H8 k;
    k.u = K8[j8];
    float4 b0 = b4[2 * j8], b1 = b4[2 * j8 + 1];
    float2 f0 = __half22float2(k.h[0]);
    float2 f1 = __half22float2(k.h[1]);
    float2 f2 = __half22float2(k.h[2]);
    float2 f3 = __half22float2(k.h[3]);
    s += f0.x * b0.x + f0.y * b0.y + f1.x * b0.z + f1.y * b0.w
       + f2.x * b1.x + f2.y * b1.y + f3.x * b1.z + f3.y * b1.w;
  }
#pragma unroll
  for (int off = 32; off; off >>= 1) s += __shfl_down(s, off, 64);
  __shared__ float sbuf[4];
  int lane = threadIdx.x & 63, wid = threadIdx.x >> 6;
  if (lane == 0) sbuf[wid] = s;
  __syncthreads();
  if (threadIdx.x == 0) {
    float kb = sbuf[0] + sbuf[1] + sbuf[2] + sbuf[3];
    float eps = expf(g_eps[0]) + 0.03f;
    float gam = expf(g_gamma[0]) + 0.03f;
    float power = gam / (gam + eps);
    a[b * NN + i] = powf((1.0f / NN) / (kb + 1e-8f), power);
  }
}

// 7) Final iteration fused: Kb + Sxyz in one pass, then a and flow.
//    flow[i] = a_i*S{xyz}/(a_i*Kb + 1e-6) - p1_i
__global__ __launch_bounds__(256) void kb_flow_kernel(
    const __half* __restrict__ K, const float* __restrict__ bvec,
    const float* __restrict__ pc1, const float* __restrict__ pc2,
    const float* __restrict__ g_gamma, const float* __restrict__ g_eps,
    float* __restrict__ out) {
  int b = blockIdx.y;
  int i = blockIdx.x;
  const uint4* K8 = (const uint4*)(K + ((size_t)b * NN + i) * NN);
  const float4* b4 = (const float4*)(bvec + b * NN);
  const float4* p2x = (const float4*)(pc2 + (size_t)b * 3 * NN);
  const float4* p2y = p2x + N4;
  const float4* p2z = p2y + N4;
  float S = 0.f, Sx = 0.f, Sy = 0.f, Sz = 0.f;
  for (int j8 = threadIdx.x; j8 < N8; j8 += 256) {
    H8 k;
    k.u = K8[j8];
    float4 b0 = b4[2 * j8], b1 = b4[2 * j8 + 1];
    float2 f0 = __half22float2(k.h[0]);
    float2 f1 = __half22float2(k.h[1]);
    float2 f2 = __half22float2(k.h[2]);
    float2 f3 = __half22float2(k.h[3]);
    float w0 = f0.x * b0.x, w1 = f0.y * b0.y, w2 = f1.x * b0.z, w3 = f1.y * b0.w;
    float w4 = f2.x * b1.x, w5 = f2.y * b1.y, w6 = f3.x * b1.z, w7 = f3.y * b1.w;
    float4 x0 = p2x[2 * j8], x1 = p2x[2 * j8 + 1];
    float4 y0 = p2y[2 * j8], y1 = p2y[2 * j8 + 1];
    float4 z0 = p2z[2 * j8], z1 = p2z[2 * j8 + 1];
    S  += (w0 + w1 + w2 + w3) + (w4 + w5 + w6 + w7);
    Sx += w0 * x0.x + w1 * x0.y + w2 * x0.z + w3 * x0.w
        + w4 * x1.x + w5 * x1.y + w6 * x1.z + w7 * x1.w;
    Sy += w0 * y0.x + w1 * y0.y + w2 * y0.z + w3 * y0.w
        + w4 * y1.x + w5 * y1.y + w6 * y1.z + w7 * y1.w;
    Sz += w0 * z0.x + w1 * z0.y + w2 * z0.z + w3 * z0.w
        + w4 * z1.x + w5 * z1.y + w6 * z1.z + w7 * z1.w;
  }
#pragma unroll
  for (int off = 32; off; off >>= 1) {
    S  += __shfl_down(S, off, 64);
    Sx += __shfl_down(Sx, off, 64);
    Sy += __shfl_down(Sy, off, 64);
    Sz += __shfl_down(Sz, off, 64);
  }
  __shared__ float red[4][4];
  int lane = threadIdx.x & 63, wid = threadIdx.x >> 6;
  if (lane == 0) {
    red[wid][0] = S; red[wid][1] = Sx; red[wid][2] = Sy; red[wid][3] = Sz;
  }
  __syncthreads();
  if (threadIdx.x == 0) {
    float kb  = red[0][0] + red[1][0] + red[2][0] + red[3][0];
    float Sxt = red[0][1] + red[1][1] + red[2][1] + red[3][1];
    float Syt = red[0][2] + red[1][2] + red[2][2] + red[3][2];
    float Szt = red[0][3] + red[1][3] + red[2][3] + red[3][3];
    float eps = expf(g_eps[0]) + 0.03f;
    float gam = expf(g_gamma[0]) + 0.03f;
    float power = gam / (gam + eps);
    float av = powf((1.0f / NN) / (kb + 1e-8f), power);
    float denom = av * kb + 1e-6f;
    const float* p1 = pc1 + (size_t)b * 3 * NN;
    size_t o = ((size_t)b * NN + i) * 3;
    out[o + 0] = av * Sxt / denom - p1[0 * NN + i];
    out[o + 1] = av * Syt / denom - p1[1 * NN + i];
    out[o + 2] = av * Szt / denom - p1[2 * NN + i];
  }
}

// ---------------------------------------------------------------------------
extern "C" void kernel_launch(void* const* d_in, const int* in_sizes, int n_in,
                              void* d_out, int out_size, void* d_ws,
                              size_t ws_size, hipStream_t stream) {
  const float* pc1 = (const float*)d_in[0];
  const float* pc2 = (const float*)d_in[1];
  const float* f1 = (const float*)d_in[2];
  const float* f2 = (const float*)d_in[3];
  const float* g_gamma = (const float*)d_in[4];
  const float* g_eps = (const float*)d_in[5];
  float* out = (float*)d_out;

  // Workspace layout
  size_t off = 0;
  char* ws = (char*)d_ws;
  __half* K = (__half*)(ws + off); off += (size_t)NB * NN * NN * sizeof(__half); // 67 MB
  float* inv1 = (float*)(ws + off); off += (size_t)NB * NN * sizeof(float);
  float* inv2 = (float*)(ws + off); off += (size_t)NB * NN * sizeof(float);
  float* avec = (float*)(ws + off); off += (size_t)NB * NN * sizeof(float);
  float* bvec = (float*)(ws + off); off += (size_t)NB * NN * sizeof(float);
  float* part = (float*)(ws + off); off += (size_t)CHUNKS * NB * NN * sizeof(float); // 4 MB
  if (ws_size < off) return;  // workspace too small — fail loudly via mismatch

  norms_kernel<<<dim3(NN / 256, NB, 2), 256, 0, stream>>>(f1, f2, inv1, inv2);
  kmat_kernel<<<dim3(NN / 64, NN / 64, NB), 256, 0, stream>>>(
      f1, f2, pc1, pc2, inv1, inv2, g_eps, K);
  init_a_kernel<<<(NB * NN + 255) / 256, 256, 0, stream>>>(avec);

  for (int it = 0; it < MAX_ITER; ++it) {
    kta_kernel<<<dim3(N8 / 256, CHUNKS, NB), 256, 0, stream>>>(K, avec, part);
    b_kernel<<<dim3(N4 / 256, NB), 256, 0, stream>>>(part, bvec, g_gamma, g_eps);
    if (it < MAX_ITER - 1) {
      kb_a_kernel<<<dim3(NN, NB), 256, 0, stream>>>(K, bvec, avec, g_gamma, g_eps);
    } else {
      kb_flow_kernel<<<dim3(NN, NB), 256, 0, stream>>>(K, bvec, pc1, pc2,
                                                       g_gamma, g_eps, out);
    }
  }
}

// Round 3
// 475.021 us; speedup vs baseline: 1.7888x; 1.3770x over previous
//
#include <hip/hip_runtime.h>
#include <hip/hip_fp16.h>
#include <math.h>

// Problem constants (from setup_inputs): B=2, C=256, N=4096
#define NB 2
#define NC 256
#define NN 4096
#define N4 (NN / 4)                    // 1024 float4 per row
#define N8 (NN / 8)                    // 512 half8 (16B) per row
#define CHUNKS 128                     // row-chunks for K^T a partials
#define ROWS_PER_CHUNK (NN / CHUNKS)   // 32
#define MAX_ITER 10

#define LDA 72                         // padded LDS row stride (halfs): 144 B, 16B-aligned

union H8 { uint4 u; __half2 h[4]; };

typedef _Float16 half8_t __attribute__((ext_vector_type(8)));
typedef float f32x4 __attribute__((ext_vector_type(4)));

// ---------------------------------------------------------------------------
// 1) inv_norm[b,n] = 1/sqrt(sum_c feats[b,c,n]^2 + 1e-6)
__global__ __launch_bounds__(256) void norms_kernel(
    const float* __restrict__ f1, const float* __restrict__ f2,
    float* __restrict__ inv1, float* __restrict__ inv2) {
  int n = blockIdx.x * 256 + threadIdx.x;
  int b = blockIdx.y;
  const float* f = blockIdx.z ? f2 : f1;
  float* o = blockIdx.z ? inv2 : inv1;
  const float* base = f + (size_t)b * NC * NN + n;
  float s = 0.f;
#pragma unroll 8
  for (int c = 0; c < NC; ++c) {
    float v = base[(size_t)c * NN];
    s = fmaf(v, v, s);
  }
  o[b * NN + n] = 1.0f / sqrtf(s + 1e-6f);
}

// ---------------------------------------------------------------------------
// 1b) prep: f_t[b][n][c] = f[b][c][n] * inv[b][n], cast to f16.
// 64x64 tile transpose via LDS. grid (NN/64, NC/64, NB*2), block 256.
__global__ __launch_bounds__(256) void prep_kernel(
    const float* __restrict__ f1, const float* __restrict__ f2,
    const float* __restrict__ inv1, const float* __restrict__ inv2,
    __half* __restrict__ f1t, __half* __restrict__ f2t) {
  int which = blockIdx.z & 1;
  int b = blockIdx.z >> 1;
  const float* f = which ? f2 : f1;
  const float* inv = which ? inv2 : inv1;
  __half* ft = which ? f2t : f1t;
  int n0 = blockIdx.x * 64;
  int c0 = blockIdx.y * 64;

  __shared__ float T[64][65];
  int t = threadIdx.x;
  int lane = t & 63, grp = t >> 6;
#pragma unroll
  for (int p = 0; p < 16; ++p) {
    int c_in = p * 4 + grp;
    T[lane][c_in] = f[((size_t)b * NC + c0 + c_in) * NN + n0 + lane];
  }
  __syncthreads();
#pragma unroll
  for (int p = 0; p < 16; ++p) {
    int n_out = p * 4 + grp;
    float v = T[n_out][lane] * inv[b * NN + n0 + n_out];
    ft[((size_t)b * NN + n0 + n_out) * NC + c0 + lane] = __float2half(v);
  }
}

// ---------------------------------------------------------------------------
// 2) K[b,i,j] = exp((corr-1)/eps') * (dist < 0.25) via f16 MFMA.
// corr[i,j] = sum_c f1t[i][c]*f2t[j][c]  (inputs pre-normalized).
// 128x128 tile, BK=64, 4 waves (2x2), each wave 64x64 = 4x4 MFMA 16x16x32.
struct __align__(16) SMstage { __half A[128 * LDA]; __half B[128 * LDA]; };
union SMu { SMstage st; __half C[128 * 128]; };

__global__ __launch_bounds__(256) void kmat_mfma_kernel(
    const __half* __restrict__ f1t, const __half* __restrict__ f2t,
    const float* __restrict__ pc1, const float* __restrict__ pc2,
    const float* __restrict__ g_eps, __half* __restrict__ K) {
  int b = blockIdx.z;
  int i0 = blockIdx.y * 128;
  int j0 = blockIdx.x * 128;

  __shared__ SMu sm;
  __shared__ float p1s[4][128];  // x,y,z,|p|^2 for rows
  __shared__ float p2s[4][128];  // for cols

  int tid = threadIdx.x;
  // Prologue: point data for epilogue
  if (tid < 128) {
    int i = i0 + tid;
    float x = pc1[((size_t)b * 3 + 0) * NN + i];
    float y = pc1[((size_t)b * 3 + 1) * NN + i];
    float z = pc1[((size_t)b * 3 + 2) * NN + i];
    p1s[0][tid] = x; p1s[1][tid] = y; p1s[2][tid] = z;
    p1s[3][tid] = x * x + y * y + z * z;
  } else {
    int j = j0 + tid - 128;
    float x = pc2[((size_t)b * 3 + 0) * NN + j];
    float y = pc2[((size_t)b * 3 + 1) * NN + j];
    float z = pc2[((size_t)b * 3 + 2) * NN + j];
    p2s[0][tid - 128] = x; p2s[1][tid - 128] = y; p2s[2][tid - 128] = z;
    p2s[3][tid - 128] = x * x + y * y + z * z;
  }
  float inv_eps = 1.0f / (expf(g_eps[0]) + 0.03f);

  const __half* Ag = f1t + ((size_t)b * NN + i0) * NC;
  const __half* Bg = f2t + ((size_t)b * NN + j0) * NC;

  int lane = tid & 63, wid = tid >> 6;
  int m0 = (wid >> 1) * 64, n0 = (wid & 1) * 64;
  int l15 = lane & 15, quad = lane >> 4;

  f32x4 acc[4][4] = {};

  int sr = tid >> 1, sh = tid & 1;  // staging: row, half-of-row

  for (int kk = 0; kk < NC; kk += 64) {
    __syncthreads();  // also covers p1s/p2s visibility on first iter
    {
      const uint4* As = (const uint4*)(Ag + (size_t)sr * NC + kk + sh * 32);
      const uint4* Bs = (const uint4*)(Bg + (size_t)sr * NC + kk + sh * 32);
      uint4* Ad = (uint4*)&sm.st.A[sr * LDA + sh * 32];
      uint4* Bd = (uint4*)&sm.st.B[sr * LDA + sh * 32];
#pragma unroll
      for (int s = 0; s < 4; ++s) Ad[s] = As[s];
#pragma unroll
      for (int s = 0; s < 4; ++s) Bd[s] = Bs[s];
    }
    __syncthreads();
#pragma unroll
    for (int ks = 0; ks < 2; ++ks) {
      half8_t aF[4], bF[4];
#pragma unroll
      for (int mt = 0; mt < 4; ++mt)
        aF[mt] = *(const half8_t*)&sm.st.A[(m0 + mt * 16 + l15) * LDA + ks * 32 + quad * 8];
#pragma unroll
      for (int nt = 0; nt < 4; ++nt)
        bF[nt] = *(const half8_t*)&sm.st.B[(n0 + nt * 16 + l15) * LDA + ks * 32 + quad * 8];
#pragma unroll
      for (int mt = 0; mt < 4; ++mt)
#pragma unroll
        for (int nt = 0; nt < 4; ++nt)
          acc[mt][nt] = __builtin_amdgcn_mfma_f32_16x16x32_f16(
              aF[mt], bF[nt], acc[mt][nt], 0, 0, 0);
    }
  }

  __syncthreads();  // done with st.A/st.B; reuse as C

  // Epilogue: per-lane col data (4 cols), row data (16 rows), exp, LDS write.
  float c2x[4], c2y[4], c2z[4], c2n[4];
#pragma unroll
  for (int nt = 0; nt < 4; ++nt) {
    int c = n0 + nt * 16 + l15;
    c2x[nt] = p2s[0][c]; c2y[nt] = p2s[1][c];
    c2z[nt] = p2s[2][c]; c2n[nt] = p2s[3][c];
  }
#pragma unroll
  for (int mt = 0; mt < 4; ++mt) {
#pragma unroll
    for (int rr = 0; rr < 4; ++rr) {
      int row = m0 + mt * 16 + quad * 4 + rr;
      float px = p1s[0][row], py = p1s[1][row], pz = p1s[2][row];
      float n1 = p1s[3][row];
#pragma unroll
      for (int nt = 0; nt < 4; ++nt) {
        float corr = acc[mt][nt][rr];
        float dist = n1 + c2n[nt] - 2.0f * (px * c2x[nt] + py * c2y[nt] + pz * c2z[nt]);
        float kv = (dist < 0.25f) ? __expf((corr - 1.0f) * inv_eps) : 0.0f;
        sm.C[row * 128 + n0 + nt * 16 + l15] = __float2half(kv);
      }
    }
  }
  __syncthreads();

  // Cooperative coalesced store: 16 threads cover a 256B row.
  int c16 = tid & 15, rg = tid >> 4;
#pragma unroll
  for (int s = 0; s < 8; ++s) {
    int row = s * 16 + rg;
    uint4 v = *(uint4*)&sm.C[row * 128 + c16 * 8];
    *(uint4*)&K[((size_t)b * NN + i0 + row) * NN + j0 + c16 * 8] = v;
  }
}

// ---------------------------------------------------------------------------
// 3) a init: a = 1/N
__global__ void init_a_kernel(float* __restrict__ a) {
  int idx = blockIdx.x * 256 + threadIdx.x;
  if (idx < NB * NN) a[idx] = 1.0f / NN;
}

// 4) K^T a partials: part[chunk,b,j] = sum_{i in chunk} K[b,i,j]*a[b,i]
__global__ __launch_bounds__(256) void kta_kernel(
    const __half* __restrict__ K, const float* __restrict__ a,
    float* __restrict__ part) {
  int b = blockIdx.z;
  int chunk = blockIdx.y;
  int j8 = blockIdx.x * 256 + threadIdx.x;  // 0..N8-1
  const uint4* K8 = (const uint4*)(K + (size_t)b * NN * NN);
  const float* av = a + b * NN;
  float s[8] = {};
  int i0 = chunk * ROWS_PER_CHUNK;
#pragma unroll 4
  for (int r = 0; r < ROWS_PER_CHUNK; ++r) {
    int i = i0 + r;
    float w = av[i];
    H8 k;
    k.u = K8[(size_t)i * N8 + j8];
#pragma unroll
    for (int q = 0; q < 4; ++q) {
      float2 f = __half22float2(k.h[q]);
      s[2 * q]     = fmaf(f.x, w, s[2 * q]);
      s[2 * q + 1] = fmaf(f.y, w, s[2 * q + 1]);
    }
  }
  float4* p = (float4*)(part + ((size_t)chunk * NB + b) * NN + j8 * 8);
  p[0] = make_float4(s[0], s[1], s[2], s[3]);
  p[1] = make_float4(s[4], s[5], s[6], s[7]);
}

// 5) b[j] = (prob2/(KTa[j]+1e-8))^power  (sums the partials)
__global__ __launch_bounds__(256) void b_kernel(
    const float* __restrict__ part, float* __restrict__ bvec,
    const float* __restrict__ g_gamma, const float* __restrict__ g_eps) {
  int b = blockIdx.y;
  int j4 = blockIdx.x * 256 + threadIdx.x;
  const float4* p4 = (const float4*)part;
  float4 s = {0.f, 0.f, 0.f, 0.f};
  for (int c = 0; c < CHUNKS; ++c) {
    float4 v = p4[((size_t)c * NB + b) * N4 + j4];
    s.x += v.x; s.y += v.y; s.z += v.z; s.w += v.w;
  }
  float eps = expf(g_eps[0]) + 0.03f;
  float gam = expf(g_gamma[0]) + 0.03f;
  float power = gam / (gam + eps);
  const float prob2 = 1.0f / NN;
  float4 r;
  r.x = powf(prob2 / (s.x + 1e-8f), power);
  r.y = powf(prob2 / (s.y + 1e-8f), power);
  r.z = powf(prob2 / (s.z + 1e-8f), power);
  r.w = powf(prob2 / (s.w + 1e-8f), power);
  ((float4*)(bvec + b * NN))[j4] = r;
}

// 6) Kb row sums fused with a update: a[i] = (prob1/(Kb[i]+1e-8))^power
__global__ __launch_bounds__(256) void kb_a_kernel(
    const __half* __restrict__ K, const float* __restrict__ bvec,
    float* __restrict__ a, const float* __restrict__ g_gamma,
    const float* __restrict__ g_eps) {
  int b = blockIdx.y;
  int i = blockIdx.x;
  const uint4* K8 = (const uint4*)(K + ((size_t)b * NN + i) * NN);
  const float4* b4 = (const float4*)(bvec + b * NN);
  float s = 0.f;
  for (int j8 = threadIdx.x; j8 < N8; j8 += 256) {
    H8 k;
    k.u = K8[j8];
    float4 b0 = b4[2 * j8], b1 = b4[2 * j8 + 1];
    float2 f0 = __half22float2(k.h[0]);
    float2 f1 = __half22float2(k.h[1]);
    float2 f2 = __half22float2(k.h[2]);
    float2 f3 = __half22float2(k.h[3]);
    s += f0.x * b0.x + f0.y * b0.y + f1.x * b0.z + f1.y * b0.w
       + f2.x * b1.x + f2.y * b1.y + f3.x * b1.z + f3.y * b1.w;
  }
#pragma unroll
  for (int off = 32; off; off >>= 1) s += __shfl_down(s, off, 64);
  __shared__ float sbuf[4];
  int lane = threadIdx.x & 63, wid = threadIdx.x >> 6;
  if (lane == 0) sbuf[wid] = s;
  __syncthreads();
  if (threadIdx.x == 0) {
    float kb = sbuf[0] + sbuf[1] + sbuf[2] + sbuf[3];
    float eps = expf(g_eps[0]) + 0.03f;
    float gam = expf(g_gamma[0]) + 0.03f;
    float power = gam / (gam + eps);
    a[b * NN + i] = powf((1.0f / NN) / (kb + 1e-8f), power);
  }
}

// 7) Final iteration fused: Kb + Sxyz in one pass, then a and flow.
__global__ __launch_bounds__(256) void kb_flow_kernel(
    const __half* __restrict__ K, const float* __restrict__ bvec,
    const float* __restrict__ pc1, const float* __restrict__ pc2,
    const float* __restrict__ g_gamma, const float* __restrict__ g_eps,
    float* __restrict__ out) {
  int b = blockIdx.y;
  int i = blockIdx.x;
  const uint4* K8 = (const uint4*)(K + ((size_t)b * NN + i) * NN);
  const float4* b4 = (const float4*)(bvec + b * NN);
  const float4* p2x = (const float4*)(pc2 + (size_t)b * 3 * NN);
  const float4* p2y = p2x + N4;
  const float4* p2z = p2y + N4;
  float S = 0.f, Sx = 0.f, Sy = 0.f, Sz = 0.f;
  for (int j8 = threadIdx.x; j8 < N8; j8 += 256) {
    H8 k;
    k.u = K8[j8];
    float4 b0 = b4[2 * j8], b1 = b4[2 * j8 + 1];
    float2 f0 = __half22float2(k.h[0]);
    float2 f1 = __half22float2(k.h[1]);
    float2 f2 = __half22float2(k.h[2]);
    float2 f3 = __half22float2(k.h[3]);
    float w0 = f0.x * b0.x, w1 = f0.y * b0.y, w2 = f1.x * b0.z, w3 = f1.y * b0.w;
    float w4 = f2.x * b1.x, w5 = f2.y * b1.y, w6 = f3.x * b1.z, w7 = f3.y * b1.w;
    float4 x0 = p2x[2 * j8], x1 = p2x[2 * j8 + 1];
    float4 y0 = p2y[2 * j8], y1 = p2y[2 * j8 + 1];
    float4 z0 = p2z[2 * j8], z1 = p2z[2 * j8 + 1];
    S  += (w0 + w1 + w2 + w3) + (w4 + w5 + w6 + w7);
    Sx += w0 * x0.x + w1 * x0.y + w2 * x0.z + w3 * x0.w
        + w4 * x1.x + w5 * x1.y + w6 * x1.z + w7 * x1.w;
    Sy += w0 * y0.x + w1 * y0.y + w2 * y0.z + w3 * y0.w
        + w4 * y1.x + w5 * y1.y + w6 * y1.z + w7 * y1.w;
    Sz += w0 * z0.x + w1 * z0.y + w2 * z0.z + w3 * z0.w
        + w4 * z1.x + w5 * z1.y + w6 * z1.z + w7 * z1.w;
  }
#pragma unroll
  for (int off = 32; off; off >>= 1) {
    S  += __shfl_down(S, off, 64);
    Sx += __shfl_down(Sx, off, 64);
    Sy += __shfl_down(Sy, off, 64);
    Sz += __shfl_down(Sz, off, 64);
  }
  __shared__ float red[4][4];
  int lane = threadIdx.x & 63, wid = threadIdx.x >> 6;
  if (lane == 0) {
    red[wid][0] = S; red[wid][1] = Sx; red[wid][2] = Sy; red[wid][3] = Sz;
  }
  __syncthreads();
  if (threadIdx.x == 0) {
    float kb  = red[0][0] + red[1][0] + red[2][0] + red[3][0];
    float Sxt = red[0][1] + red[1][1] + red[2][1] + red[3][1];
    float Syt = red[0][2] + red[1][2] + red[2][2] + red[3][2];
    float Szt = red[0][3] + red[1][3] + red[2][3] + red[3][3];
    float eps = expf(g_eps[0]) + 0.03f;
    float gam = expf(g_gamma[0]) + 0.03f;
    float power = gam / (gam + eps);
    float av = powf((1.0f / NN) / (kb + 1e-8f), power);
    float denom = av * kb + 1e-6f;
    const float* p1 = pc1 + (size_t)b * 3 * NN;
    size_t o = ((size_t)b * NN + i) * 3;
    out[o + 0] = av * Sxt / denom - p1[0 * NN + i];
    out[o + 1] = av * Syt / denom - p1[1 * NN + i];
    out[o + 2] = av * Szt / denom - p1[2 * NN + i];
  }
}

// ---------------------------------------------------------------------------
extern "C" void kernel_launch(void* const* d_in, const int* in_sizes, int n_in,
                              void* d_out, int out_size, void* d_ws,
                              size_t ws_size, hipStream_t stream) {
  const float* pc1 = (const float*)d_in[0];
  const float* pc2 = (const float*)d_in[1];
  const float* f1 = (const float*)d_in[2];
  const float* f2 = (const float*)d_in[3];
  const float* g_gamma = (const float*)d_in[4];
  const float* g_eps = (const float*)d_in[5];
  float* out = (float*)d_out;

  // Workspace layout
  size_t off = 0;
  char* ws = (char*)d_ws;
  __half* K = (__half*)(ws + off); off += (size_t)NB * NN * NN * sizeof(__half); // 67 MB
  __half* f1t = (__half*)(ws + off); off += (size_t)NB * NN * NC * sizeof(__half); // 4 MB
  __half* f2t = (__half*)(ws + off); off += (size_t)NB * NN * NC * sizeof(__half); // 4 MB
  float* inv1 = (float*)(ws + off); off += (size_t)NB * NN * sizeof(float);
  float* inv2 = (float*)(ws + off); off += (size_t)NB * NN * sizeof(float);
  float* avec = (float*)(ws + off); off += (size_t)NB * NN * sizeof(float);
  float* bvec = (float*)(ws + off); off += (size_t)NB * NN * sizeof(float);
  float* part = (float*)(ws + off); off += (size_t)CHUNKS * NB * NN * sizeof(float); // 4 MB
  if (ws_size < off) return;  // workspace too small

  norms_kernel<<<dim3(NN / 256, NB, 2), 256, 0, stream>>>(f1, f2, inv1, inv2);
  prep_kernel<<<dim3(NN / 64, NC / 64, NB * 2), 256, 0, stream>>>(
      f1, f2, inv1, inv2, f1t, f2t);
  kmat_mfma_kernel<<<dim3(NN / 128, NN / 128, NB), 256, 0, stream>>>(
      f1t, f2t, pc1, pc2, g_eps, K);
  init_a_kernel<<<(NB * NN + 255) / 256, 256, 0, stream>>>(avec);

  for (int it = 0; it < MAX_ITER; ++it) {
    kta_kernel<<<dim3(N8 / 256, CHUNKS, NB), 256, 0, stream>>>(K, avec, part);
    b_kernel<<<dim3(N4 / 256, NB), 256, 0, stream>>>(part, bvec, g_gamma, g_eps);
    if (it < MAX_ITER - 1) {
      kb_a_kernel<<<dim3(NN, NB), 256, 0, stream>>>(K, bvec, avec, g_gamma, g_eps);
    } else {
      kb_flow_kernel<<<dim3(NN, NB), 256, 0, stream>>>(K, bvec, pc1, pc2,
                                                       g_gamma, g_eps, out);
    }
  }
}